// Round 1
// baseline (312.274 us; speedup 1.0000x reference)
//
#include <hip/hip_runtime.h>
#include <hip/hip_bf16.h>
#include <cstdint>

// VQ quantizer: dist argmin over 8192 codes, gather, loss.
// Strategy: bf16 hi/lo split GEMM on MFMA (3 passes) + fused argmin via
// 64-bit atomicMin keys; exact-f32 gather + deterministic loss reduce.

typedef __bf16 bf16x8 __attribute__((ext_vector_type(8)));
typedef __bf16 bf16x4 __attribute__((ext_vector_type(4)));
typedef float  f32x4  __attribute__((ext_vector_type(4)));

#define N_ROWS  16384
#define N_CODES 8192
#define DDIM    256

#define STAGE16(gptr, lptr) __builtin_amdgcn_global_load_lds( \
    (const __attribute__((address_space(1))) void*)(gptr),    \
    (__attribute__((address_space(3))) void*)(lptr), 16, 0, 0)

// ---------- prep: split x (f32) into bf16 hi/lo planes ----------
__global__ void prep_x_k(const float* __restrict__ x,
                         __bf16* __restrict__ xhi, __bf16* __restrict__ xlo) {
  int i = blockIdx.x * 256 + threadIdx.x;            // 1,048,576 threads * 4 elems
  float4 v = reinterpret_cast<const float4*>(x)[i];
  float a[4] = {v.x, v.y, v.z, v.w};
  bf16x4 h, l;
#pragma unroll
  for (int j = 0; j < 4; ++j) {
    __bf16 hh = (__bf16)a[j];
    h[j] = hh;
    l[j] = (__bf16)(a[j] - (float)hh);
  }
  reinterpret_cast<bf16x4*>(xhi)[i] = h;
  reinterpret_cast<bf16x4*>(xlo)[i] = l;
}

// ---------- prep: transpose emb [256][8192] -> [8192][256]; split + exact f32 copy ----------
__global__ void prep_e_k(const float* __restrict__ emb,
                         __bf16* __restrict__ ehi, __bf16* __restrict__ elo,
                         float* __restrict__ embT) {
  __shared__ float tile[64][65];
  const int kb = blockIdx.x * 64, db = blockIdx.y * 64;
  const int t = threadIdx.x;
  const int tk = t & 63, td = t >> 6;                // td 0..3
#pragma unroll
  for (int c = 0; c < 16; ++c) {
    int d = c * 4 + td;
    tile[d][tk] = emb[(size_t)(db + d) * N_CODES + kb + tk];
  }
  __syncthreads();
#pragma unroll
  for (int c = 0; c < 16; ++c) {
    int k = c * 4 + td;
    int d = tk;
    float v = tile[d][k];
    size_t o = (size_t)(kb + k) * DDIM + db + d;
    __bf16 h = (__bf16)v;
    embT[o] = v;
    ehi[o] = h;
    elo[o] = (__bf16)(v - (float)h);
  }
}

// ---------- prep: ||e_k||^2 in exact f32 ----------
__global__ void enorm_k(const float* __restrict__ emb, float* __restrict__ enorm) {
  int k = blockIdx.x * 256 + threadIdx.x;
  float s = 0.f;
  for (int d = 0; d < DDIM; ++d) {
    float v = emb[(size_t)d * N_CODES + k];
    s += v * v;
  }
  enorm[k] = s;
}

// ---------- main: 128x128 tile GEMM (3-pass bf16 split) + fused argmin ----------
__global__ __launch_bounds__(256, 2) void vq_main_k(
    const __bf16* __restrict__ xhi, const __bf16* __restrict__ xlo,
    const __bf16* __restrict__ ehi, const __bf16* __restrict__ elo,
    const float* __restrict__ enorm, unsigned long long* __restrict__ keys) {
  __shared__ alignas(16) __bf16 Ah[128][64];
  __shared__ alignas(16) __bf16 Al[128][64];
  __shared__ alignas(16) __bf16 Bh[128][64];
  __shared__ alignas(16) __bf16 Bl[128][64];

  const int tid = threadIdx.x;
  const int wid = tid >> 6, lane = tid & 63;
  const int bm = blockIdx.x, bn = blockIdx.y;
  const int wr = wid >> 1, wc = wid & 1;             // 2x2 waves, 64x64 each

  f32x4 acc[4][4] = {};

  const int srow = lane >> 3;                        // 0..7
  const int scol = (lane & 7) * 8;                   // bf16 element col
  const size_t abase = (size_t)(bm * 128) * DDIM;
  const size_t bbase = (size_t)(bn * 128) * DDIM;

  for (int kt = 0; kt < DDIM / 64; ++kt) {
    const int k0 = kt * 64;
    // stage 4 planes: per wave 4 calls/plane, each call = 64 lanes * 16B = 8 rows
#pragma unroll
    for (int c = 0; c < 4; ++c) {
      const int r0 = wid * 32 + c * 8;
      const size_t go = (size_t)(r0 + srow) * DDIM + k0 + scol;
      STAGE16(xhi + abase + go, &Ah[r0][0]);
      STAGE16(xlo + abase + go, &Al[r0][0]);
      STAGE16(ehi + bbase + go, &Bh[r0][0]);
      STAGE16(elo + bbase + go, &Bl[r0][0]);
    }
    __syncthreads();
#pragma unroll
    for (int kk = 0; kk < 2; ++kk) {
      bf16x8 a_h[4], a_l[4], b_h[4], b_l[4];
      const int kcol = kk * 32 + (lane >> 4) * 8;
#pragma unroll
      for (int m = 0; m < 4; ++m) {
        const int row = wr * 64 + m * 16 + (lane & 15);
        a_h[m] = *(const bf16x8*)&Ah[row][kcol];
        a_l[m] = *(const bf16x8*)&Al[row][kcol];
      }
#pragma unroll
      for (int n = 0; n < 4; ++n) {
        const int row = wc * 64 + n * 16 + (lane & 15);
        b_h[n] = *(const bf16x8*)&Bh[row][kcol];
        b_l[n] = *(const bf16x8*)&Bl[row][kcol];
      }
#pragma unroll
      for (int m = 0; m < 4; ++m)
#pragma unroll
        for (int n = 0; n < 4; ++n) {
          acc[m][n] = __builtin_amdgcn_mfma_f32_16x16x32_bf16(a_h[m], b_h[n], acc[m][n], 0, 0, 0);
          acc[m][n] = __builtin_amdgcn_mfma_f32_16x16x32_bf16(a_h[m], b_l[n], acc[m][n], 0, 0, 0);
          acc[m][n] = __builtin_amdgcn_mfma_f32_16x16x32_bf16(a_l[m], b_h[n], acc[m][n], 0, 0, 0);
        }
    }
    __syncthreads();
  }

  // epilogue: score = ||e||^2 - 2*dot ; per-row argmin -> 64-bit key atomicMin
  const int codeBase = bn * 128 + wc * 64 + (lane & 15);
  float en[4];
#pragma unroll
  for (int n = 0; n < 4; ++n) en[n] = enorm[codeBase + n * 16];
  const int rowBase = bm * 128 + wr * 64 + ((lane >> 4) << 2);
#pragma unroll
  for (int m = 0; m < 4; ++m) {
#pragma unroll
    for (int r = 0; r < 4; ++r) {
      unsigned long long best = ~0ull;
#pragma unroll
      for (int n = 0; n < 4; ++n) {
        float sc = en[n] - 2.0f * acc[m][n][r];
        unsigned u = __float_as_uint(sc);
        u = (u & 0x80000000u) ? ~u : (u | 0x80000000u);   // order-preserving f32->u32
        unsigned long long key = ((unsigned long long)u << 32) | (unsigned)(codeBase + n * 16);
        best = key < best ? key : best;
      }
#pragma unroll
      for (int mk = 1; mk <= 8; mk <<= 1) {               // min across the 16-lane col group
        unsigned lo32 = (unsigned)best, hi32 = (unsigned)(best >> 32);
        lo32 = __shfl_xor(lo32, mk, 64);
        hi32 = __shfl_xor(hi32, mk, 64);
        unsigned long long o = ((unsigned long long)hi32 << 32) | lo32;
        best = o < best ? o : best;
      }
      if ((lane & 15) == 0) atomicMin(&keys[rowBase + m * 16 + r], best);
    }
  }
}

// ---------- gather q (exact f32), q_st out, per-row squared error ----------
__global__ void gather_k(const float* __restrict__ x, const float* __restrict__ embT,
                         const unsigned long long* __restrict__ keys,
                         float* __restrict__ qout, float* __restrict__ rowsum) {
  const int row = blockIdx.x;
  const int lane = threadIdx.x;                      // 64 threads, 4 floats each
  const int idx = (int)(keys[row] & 0xffffffffull);
  float4 q  = reinterpret_cast<const float4*>(embT + (size_t)idx * DDIM)[lane];
  float4 xv = reinterpret_cast<const float4*>(x + (size_t)row * DDIM)[lane];
  reinterpret_cast<float4*>(qout + (size_t)row * DDIM)[lane] = q;
  float dx = q.x - xv.x, dy = q.y - xv.y, dz = q.z - xv.z, dw = q.w - xv.w;
  float s = dx * dx + dy * dy + dz * dz + dw * dw;
#pragma unroll
  for (int mk = 32; mk; mk >>= 1) s += __shfl_xor(s, mk, 64);
  if (lane == 0) rowsum[row] = s;
}

// ---------- deterministic final loss reduce ----------
__global__ void loss_k(const float* __restrict__ rowsum, float* __restrict__ out) {
  __shared__ float sm[4];
  const int t = threadIdx.x;
  float s = 0.f;
  for (int j = t; j < N_ROWS; j += 256) s += rowsum[j];
#pragma unroll
  for (int mk = 32; mk; mk >>= 1) s += __shfl_xor(s, mk, 64);
  if ((t & 63) == 0) sm[t >> 6] = s;
  __syncthreads();
  if (t == 0) out[0] = 2.0f * (sm[0] + sm[1] + sm[2] + sm[3]) / (float)(N_ROWS * DDIM);
}

extern "C" void kernel_launch(void* const* d_in, const int* in_sizes, int n_in,
                              void* d_out, int out_size, void* d_ws, size_t ws_size,
                              hipStream_t stream) {
  const float* x   = (const float*)d_in[0];          // [16,1024,256] f32
  const float* emb = (const float*)d_in[1];          // [256,8192] f32
  float* qout = (float*)d_out;                       // 4,194,304 q_st + 1 loss

  // workspace layout (~32.2 MB total)
  char* w = (char*)d_ws;
  unsigned long long* keys = (unsigned long long*)w;                 // 131072 B
  float* rowsum = (float*)(w + 131072);                              // 65536 B
  __bf16* xhi = (__bf16*)(w + 196608);                               // 8 MB
  __bf16* xlo = xhi + (size_t)N_ROWS * DDIM;                         // 8 MB
  __bf16* ehi = xlo + (size_t)N_ROWS * DDIM;                         // 4 MB
  __bf16* elo = ehi + (size_t)N_CODES * DDIM;                        // 4 MB
  float*  embT = (float*)(elo + (size_t)N_CODES * DDIM);             // 8 MB
  float*  enorm = embT + (size_t)N_CODES * DDIM;                     // 32 KB

  hipMemsetAsync(keys, 0xFF, N_ROWS * sizeof(unsigned long long), stream);
  prep_x_k<<<4096, 256, 0, stream>>>(x, xhi, xlo);
  prep_e_k<<<dim3(N_CODES / 64, DDIM / 64), 256, 0, stream>>>(emb, ehi, elo, embT);
  enorm_k<<<N_CODES / 256, 256, 0, stream>>>(emb, enorm);
  vq_main_k<<<dim3(N_ROWS / 128, N_CODES / 128), 256, 0, stream>>>(xhi, xlo, ehi, elo, enorm, keys);
  gather_k<<<N_ROWS, 64, 0, stream>>>(x, embT, keys, qout, rowsum);
  loss_k<<<1, 256, 0, stream>>>(rowsum, qout + (size_t)N_ROWS * DDIM);
}

// Round 2
// 300.208 us; speedup vs baseline: 1.0402x; 1.0402x over previous
//
#include <hip/hip_runtime.h>
#include <hip/hip_bf16.h>
#include <cstdint>

// VQ quantizer: dist argmin over 8192 codes, gather, loss.
// bf16 hi/lo split GEMM on MFMA (3 passes: hh + hl + lh) + fused argmin via
// 64-bit atomicMin keys; exact-f32 gather + deterministic loss reduce.
// R2: T2 XOR-swizzle on LDS tiles (pre-swizzled global source + swizzled
// ds_read chunk) to kill the 16-way bank conflict (5e7 cycles in R1).

typedef __bf16 bf16x8 __attribute__((ext_vector_type(8)));
typedef __bf16 bf16x4 __attribute__((ext_vector_type(4)));
typedef float  f32x4  __attribute__((ext_vector_type(4)));

#define N_ROWS  16384
#define N_CODES 8192
#define DDIM    256

#define STAGE16(gptr, lptr) __builtin_amdgcn_global_load_lds( \
    (const __attribute__((address_space(1))) void*)(gptr),    \
    (__attribute__((address_space(3))) void*)(lptr), 16, 0, 0)

// ---------- prep: split x (f32) into bf16 hi/lo planes ----------
__global__ void prep_x_k(const float* __restrict__ x,
                         __bf16* __restrict__ xhi, __bf16* __restrict__ xlo) {
  int i = blockIdx.x * 256 + threadIdx.x;            // 1,048,576 threads * 4 elems
  float4 v = reinterpret_cast<const float4*>(x)[i];
  float a[4] = {v.x, v.y, v.z, v.w};
  bf16x4 h, l;
#pragma unroll
  for (int j = 0; j < 4; ++j) {
    __bf16 hh = (__bf16)a[j];
    h[j] = hh;
    l[j] = (__bf16)(a[j] - (float)hh);
  }
  reinterpret_cast<bf16x4*>(xhi)[i] = h;
  reinterpret_cast<bf16x4*>(xlo)[i] = l;
}

// ---------- prep: transpose emb [256][8192] -> [8192][256]; split + exact f32 copy ----------
__global__ void prep_e_k(const float* __restrict__ emb,
                         __bf16* __restrict__ ehi, __bf16* __restrict__ elo,
                         float* __restrict__ embT) {
  __shared__ float tile[64][65];
  const int kb = blockIdx.x * 64, db = blockIdx.y * 64;
  const int t = threadIdx.x;
  const int tk = t & 63, td = t >> 6;                // td 0..3
#pragma unroll
  for (int c = 0; c < 16; ++c) {
    int d = c * 4 + td;
    tile[d][tk] = emb[(size_t)(db + d) * N_CODES + kb + tk];
  }
  __syncthreads();
#pragma unroll
  for (int c = 0; c < 16; ++c) {
    int k = c * 4 + td;
    int d = tk;
    float v = tile[d][k];
    size_t o = (size_t)(kb + k) * DDIM + db + d;
    __bf16 h = (__bf16)v;
    embT[o] = v;
    ehi[o] = h;
    elo[o] = (__bf16)(v - (float)h);
  }
}

// ---------- prep: ||e_k||^2 in exact f32 ----------
__global__ void enorm_k(const float* __restrict__ emb, float* __restrict__ enorm) {
  int k = blockIdx.x * 256 + threadIdx.x;
  float s = 0.f;
  for (int d = 0; d < DDIM; ++d) {
    float v = emb[(size_t)d * N_CODES + k];
    s += v * v;
  }
  enorm[k] = s;
}

// ---------- main: 128x128 tile GEMM (3-pass bf16 split) + fused argmin ----------
// LDS layout: linear dest for global_load_lds; data for logical (row, chunk)
// lives at LDS chunk (chunk ^ (row&7)). Staging pre-swizzles the GLOBAL source
// chunk; reads XOR the chunk. (rule #21: both-sides-or-neither)
__global__ __launch_bounds__(256, 2) void vq_main_k(
    const __bf16* __restrict__ xhi, const __bf16* __restrict__ xlo,
    const __bf16* __restrict__ ehi, const __bf16* __restrict__ elo,
    const float* __restrict__ enorm, unsigned long long* __restrict__ keys) {
  __shared__ alignas(16) __bf16 Ah[128][64];
  __shared__ alignas(16) __bf16 Al[128][64];
  __shared__ alignas(16) __bf16 Bh[128][64];
  __shared__ alignas(16) __bf16 Bl[128][64];

  const int tid = threadIdx.x;
  const int wid = tid >> 6, lane = tid & 63;
  const int bm = blockIdx.x, bn = blockIdx.y;
  const int wr = wid >> 1, wc = wid & 1;             // 2x2 waves, 64x64 each

  f32x4 acc[4][4] = {};

  const int srow = lane >> 3;                        // 0..7 within the 8-row stripe
  const int scol = ((lane & 7) ^ srow) * 8;          // pre-swizzled global chunk
  const size_t abase = (size_t)(bm * 128) * DDIM;
  const size_t bbase = (size_t)(bn * 128) * DDIM;

  for (int kt = 0; kt < DDIM / 64; ++kt) {
    const int k0 = kt * 64;
    // stage 4 planes: per wave 4 calls/plane, each call = 64 lanes * 16B = 8 rows
#pragma unroll
    for (int c = 0; c < 4; ++c) {
      const int r0 = wid * 32 + c * 8;
      const size_t go = (size_t)(r0 + srow) * DDIM + k0 + scol;
      STAGE16(xhi + abase + go, &Ah[r0][0]);
      STAGE16(xlo + abase + go, &Al[r0][0]);
      STAGE16(ehi + bbase + go, &Bh[r0][0]);
      STAGE16(elo + bbase + go, &Bl[r0][0]);
    }
    __syncthreads();
#pragma unroll
    for (int kk = 0; kk < 2; ++kk) {
      bf16x8 a_h[4], a_l[4], b_h[4], b_l[4];
      // logical chunk (kk*4 + lane>>4) at rows base+(lane&15): row&7 == lane&7
      const int kcol = ((kk * 4 + (lane >> 4)) ^ (lane & 7)) * 8;
#pragma unroll
      for (int m = 0; m < 4; ++m) {
        const int row = wr * 64 + m * 16 + (lane & 15);
        a_h[m] = *(const bf16x8*)&Ah[row][kcol];
        a_l[m] = *(const bf16x8*)&Al[row][kcol];
      }
#pragma unroll
      for (int n = 0; n < 4; ++n) {
        const int row = wc * 64 + n * 16 + (lane & 15);
        b_h[n] = *(const bf16x8*)&Bh[row][kcol];
        b_l[n] = *(const bf16x8*)&Bl[row][kcol];
      }
#pragma unroll
      for (int m = 0; m < 4; ++m)
#pragma unroll
        for (int n = 0; n < 4; ++n) {
          acc[m][n] = __builtin_amdgcn_mfma_f32_16x16x32_bf16(a_h[m], b_h[n], acc[m][n], 0, 0, 0);
          acc[m][n] = __builtin_amdgcn_mfma_f32_16x16x32_bf16(a_h[m], b_l[n], acc[m][n], 0, 0, 0);
          acc[m][n] = __builtin_amdgcn_mfma_f32_16x16x32_bf16(a_l[m], b_h[n], acc[m][n], 0, 0, 0);
        }
    }
    __syncthreads();
  }

  // epilogue: score = ||e||^2 - 2*dot ; per-row argmin -> 64-bit key atomicMin
  const int codeBase = bn * 128 + wc * 64 + (lane & 15);
  float en[4];
#pragma unroll
  for (int n = 0; n < 4; ++n) en[n] = enorm[codeBase + n * 16];
  const int rowBase = bm * 128 + wr * 64 + ((lane >> 4) << 2);
#pragma unroll
  for (int m = 0; m < 4; ++m) {
#pragma unroll
    for (int r = 0; r < 4; ++r) {
      unsigned long long best = ~0ull;
#pragma unroll
      for (int n = 0; n < 4; ++n) {
        float sc = en[n] - 2.0f * acc[m][n][r];
        unsigned u = __float_as_uint(sc);
        u = (u & 0x80000000u) ? ~u : (u | 0x80000000u);   // order-preserving f32->u32
        unsigned long long key = ((unsigned long long)u << 32) | (unsigned)(codeBase + n * 16);
        best = key < best ? key : best;
      }
#pragma unroll
      for (int mk = 1; mk <= 8; mk <<= 1) {               // min across the 16-lane col group
        unsigned lo32 = (unsigned)best, hi32 = (unsigned)(best >> 32);
        lo32 = __shfl_xor(lo32, mk, 64);
        hi32 = __shfl_xor(hi32, mk, 64);
        unsigned long long o = ((unsigned long long)hi32 << 32) | lo32;
        best = o < best ? o : best;
      }
      if ((lane & 15) == 0) atomicMin(&keys[rowBase + m * 16 + r], best);
    }
  }
}

// ---------- gather q (exact f32), q_st out, per-row squared error ----------
__global__ void gather_k(const float* __restrict__ x, const float* __restrict__ embT,
                         const unsigned long long* __restrict__ keys,
                         float* __restrict__ qout, float* __restrict__ rowsum) {
  const int row = blockIdx.x;
  const int lane = threadIdx.x;                      // 64 threads, 4 floats each
  const int idx = (int)(keys[row] & 0xffffffffull);
  float4 q  = reinterpret_cast<const float4*>(embT + (size_t)idx * DDIM)[lane];
  float4 xv = reinterpret_cast<const float4*>(x + (size_t)row * DDIM)[lane];
  reinterpret_cast<float4*>(qout + (size_t)row * DDIM)[lane] = q;
  float dx = q.x - xv.x, dy = q.y - xv.y, dz = q.z - xv.z, dw = q.w - xv.w;
  float s = dx * dx + dy * dy + dz * dz + dw * dw;
#pragma unroll
  for (int mk = 32; mk; mk >>= 1) s += __shfl_xor(s, mk, 64);
  if (lane == 0) rowsum[row] = s;
}

// ---------- deterministic final loss reduce ----------
__global__ void loss_k(const float* __restrict__ rowsum, float* __restrict__ out) {
  __shared__ float sm[4];
  const int t = threadIdx.x;
  float s = 0.f;
  for (int j = t; j < N_ROWS; j += 256) s += rowsum[j];
#pragma unroll
  for (int mk = 32; mk; mk >>= 1) s += __shfl_xor(s, mk, 64);
  if ((t & 63) == 0) sm[t >> 6] = s;
  __syncthreads();
  if (t == 0) out[0] = 2.0f * (sm[0] + sm[1] + sm[2] + sm[3]) / (float)(N_ROWS * DDIM);
}

extern "C" void kernel_launch(void* const* d_in, const int* in_sizes, int n_in,
                              void* d_out, int out_size, void* d_ws, size_t ws_size,
                              hipStream_t stream) {
  const float* x   = (const float*)d_in[0];          // [16,1024,256] f32
  const float* emb = (const float*)d_in[1];          // [256,8192] f32
  float* qout = (float*)d_out;                       // 4,194,304 q_st + 1 loss

  // workspace layout (~32.2 MB total)
  char* w = (char*)d_ws;
  unsigned long long* keys = (unsigned long long*)w;                 // 131072 B
  float* rowsum = (float*)(w + 131072);                              // 65536 B
  __bf16* xhi = (__bf16*)(w + 196608);                               // 8 MB
  __bf16* xlo = xhi + (size_t)N_ROWS * DDIM;                         // 8 MB
  __bf16* ehi = xlo + (size_t)N_ROWS * DDIM;                         // 4 MB
  __bf16* elo = ehi + (size_t)N_CODES * DDIM;                        // 4 MB
  float*  embT = (float*)(elo + (size_t)N_CODES * DDIM);             // 8 MB
  float*  enorm = embT + (size_t)N_CODES * DDIM;                     // 32 KB

  hipMemsetAsync(keys, 0xFF, N_ROWS * sizeof(unsigned long long), stream);
  prep_x_k<<<4096, 256, 0, stream>>>(x, xhi, xlo);
  prep_e_k<<<dim3(N_CODES / 64, DDIM / 64), 256, 0, stream>>>(emb, ehi, elo, embT);
  enorm_k<<<N_CODES / 256, 256, 0, stream>>>(emb, enorm);
  vq_main_k<<<dim3(N_ROWS / 128, N_CODES / 128), 256, 0, stream>>>(xhi, xlo, ehi, elo, enorm, keys);
  gather_k<<<N_ROWS, 64, 0, stream>>>(x, embT, keys, qout, rowsum);
  loss_k<<<1, 256, 0, stream>>>(rowsum, qout + (size_t)N_ROWS * DDIM);
}